// Round 7
// baseline (107.935 us; speedup 1.0000x reference)
//
#include <hip/hip_runtime.h>

// AWQ W4A16 GEMM: x[16,4096] fp32 * dq(qweight)[4096,11008] + bias.
// Round-7 DIAGNOSTIC: r6 kernel bit-identical, but gemm body wrapped in an
// idempotent REP=3 loop so the gemm dispatch (~60us) lands in rocprof top-5
// with full PMC. Each rep: reload -> restage -> reaccumulate -> rewrite the
// same partials (race-free via the stage loop's trailing barrier).

typedef __attribute__((ext_vector_type(8))) short bf16x8;
typedef __attribute__((ext_vector_type(4))) float f32x4;

#define K_DIM 4096
#define N_DIM 11008
#define M_DIM 16
#define NPACK 1376    // N/8 packed words per k-row
#define NCB   86      // 11008 / 128 cols per block
#define REP   3       // diagnostic repeat (idempotent)

static __device__ __forceinline__ unsigned short f2bf(float f) {
  unsigned u = __builtin_bit_cast(unsigned, f);
  u += 0x7fffu + ((u >> 16) & 1u);   // RNE, finite only
  return (unsigned short)(u >> 16);
}

// grid (86, 16), block 256 (4 waves). Block: 128 cols (16 words), 256 k.
__global__ __launch_bounds__(256) void gemm_awq_fast(
    const int* __restrict__ qw, const int* __restrict__ qz,
    const float* __restrict__ scales, const float* __restrict__ x,
    float* __restrict__ part) {
  __shared__ int qt[2][16][68];

  int cb = blockIdx.x, ks = blockIdx.y;
  int n0 = cb * 128, w0 = cb * 16, k0 = ks * 256;

  int tid = threadIdx.x, lane = tid & 63, wv = tid >> 6;  // wv 0..3
  int c15 = lane & 15;
  int kg  = lane >> 4;
  int j   = c15 & 7;
  int sh  = ((j & 1) << 4) | ((j >> 1) << 2);  // AWQ {0,4,1,5,2,6,3,7} (proven)
  int wloc = wv * 4 + (c15 >> 3);

  int srow = tid >> 2, sw4 = (tid & 3) * 4;
  const int* gq = qw + (size_t)(k0 + srow) * NPACK + w0 + sw4;

  union { bf16x8 v; unsigned short u[8]; } ones;
#pragma unroll
  for (int i = 0; i < 8; ++i) ones.u[i] = 0x3F80;  // bf16 1.0

#pragma unroll 1
  for (int rep = 0; rep < REP; ++rep) {
    // ---- prologue: issue ALL 4 stage loads first ----
    int4 qreg[4];
#pragma unroll
    for (int st = 0; st < 4; ++st)
      qreg[st] = *reinterpret_cast<const int4*>(gq + (size_t)st * 64 * NPACK);

    // A fragments from fp32 x
    bf16x8 a[8];
#pragma unroll
    for (int kk = 0; kk < 8; ++kk) {
      const float* xp = x + c15 * K_DIM + k0 + kk * 32 + kg * 8;
      float4 x0 = *reinterpret_cast<const float4*>(xp);
      float4 x1 = *reinterpret_cast<const float4*>(xp + 4);
      union { bf16x8 v; unsigned short u[8]; } t;
      t.u[0] = f2bf(x0.x); t.u[1] = f2bf(x0.y);
      t.u[2] = f2bf(x0.z); t.u[3] = f2bf(x0.w);
      t.u[4] = f2bf(x1.x); t.u[5] = f2bf(x1.y);
      t.u[6] = f2bf(x1.z); t.u[7] = f2bf(x1.w);
      a[kk] = t.v;
    }

    float s[2][2], zn[2][2];
#pragma unroll
    for (int g = 0; g < 2; ++g) {
      int gid = ks * 2 + g;
#pragma unroll
      for (int c = 0; c < 2; ++c) {
        int n = n0 + wv * 32 + c * 16 + c15;
        s[g][c] = scales[gid * N_DIM + n];
        int zw = qz[gid * NPACK + w0 + wloc + 2 * c];
        zn[g][c] = -(float)(((zw >> sh) & 15) + 128);  // -(z+128)
      }
    }

    const f32x4 vzero = {0.f, 0.f, 0.f, 0.f};
    f32x4 macc[2] = {vzero, vzero};
    f32x4 pacc[2] = {vzero, vzero};
    f32x4 xacc    = vzero;

    // stage 0 into buf 0 (prior rep's last reads fenced by its final barrier)
    qt[0][sw4 + 0][srow] = qreg[0].x;
    qt[0][sw4 + 1][srow] = qreg[0].y;
    qt[0][sw4 + 2][srow] = qreg[0].z;
    qt[0][sw4 + 3][srow] = qreg[0].w;
    __syncthreads();

#pragma unroll
    for (int st = 0; st < 4; ++st) {
      const int cur = st & 1;

#pragma unroll
      for (int t2 = 0; t2 < 2; ++t2) {
        const int kk = st * 2 + t2;
#pragma unroll
        for (int c = 0; c < 2; ++c) {
          const int* cp = &qt[cur][wloc + 2 * c][t2 * 32 + kg * 8];
          int4 qa = *reinterpret_cast<const int4*>(cp);      // ds_read_b128
          int4 qb = *reinterpret_cast<const int4*>(cp + 4);  // ds_read_b128
          union { bf16x8 v; unsigned short u[8]; } b;
          b.u[0] = (unsigned short)(0x4300 | ((qa.x >> sh) & 15));
          b.u[1] = (unsigned short)(0x4300 | ((qa.y >> sh) & 15));
          b.u[2] = (unsigned short)(0x4300 | ((qa.z >> sh) & 15));
          b.u[3] = (unsigned short)(0x4300 | ((qa.w >> sh) & 15));
          b.u[4] = (unsigned short)(0x4300 | ((qb.x >> sh) & 15));
          b.u[5] = (unsigned short)(0x4300 | ((qb.y >> sh) & 15));
          b.u[6] = (unsigned short)(0x4300 | ((qb.z >> sh) & 15));
          b.u[7] = (unsigned short)(0x4300 | ((qb.w >> sh) & 15));
          pacc[c] = __builtin_amdgcn_mfma_f32_16x16x32_bf16(a[kk], b.v, pacc[c], 0, 0, 0);
        }
        xacc = __builtin_amdgcn_mfma_f32_16x16x32_bf16(a[kk], ones.v, xacc, 0, 0, 0);

        if ((kk & 3) == 3) {
          const int g = kk >> 2;
#pragma unroll
          for (int c = 0; c < 2; ++c)
#pragma unroll
            for (int r = 0; r < 4; ++r) {
              float t = fmaf(zn[g][c], xacc[r], pacc[c][r]);
              macc[c][r] = fmaf(s[g][c], t, macc[c][r]);
            }
          pacc[0] = vzero; pacc[1] = vzero; xacc = vzero;
        }
      }

      if (st < 3) {
        qt[cur ^ 1][sw4 + 0][srow] = qreg[st + 1].x;
        qt[cur ^ 1][sw4 + 1][srow] = qreg[st + 1].y;
        qt[cur ^ 1][sw4 + 2][srow] = qreg[st + 1].z;
        qt[cur ^ 1][sw4 + 3][srow] = qreg[st + 1].w;
      }
      __syncthreads();
    }

    // epilogue (idempotent across reps)
    float* pb = part + (size_t)ks * (M_DIM * N_DIM);
#pragma unroll
    for (int c = 0; c < 2; ++c) {
      int n = n0 + wv * 32 + c * 16 + c15;
#pragma unroll
      for (int r = 0; r < 4; ++r)
        pb[(kg * 4 + r) * N_DIM + n] = macc[c][r];
    }
  }
}

// Generic fallback (round-3-proven verbatim), used only if ws is tiny.
__global__ __launch_bounds__(256) void gemm_awq_generic(
    const int* __restrict__ qw, const int* __restrict__ qz,
    const float* __restrict__ scales, const float* __restrict__ x,
    float* __restrict__ part, int nstep) {
  __shared__ int qt[16][36];
  int cb = blockIdx.x, ks = blockIdx.y;
  int n0 = cb * 128, w0 = cb * 16, k0 = ks * nstep * 32;
  int tid = threadIdx.x, lane = tid & 63, wv = tid >> 6;
  int c15 = lane & 15, kg = lane >> 4;
  int j = c15 & 7;
  int sh = ((j & 1) << 4) | ((j >> 1) << 2);
  int wloc = wv * 4 + (c15 >> 3);
  int srow = tid >> 3, swd = (tid & 7) * 2;
  const int* gq = qw + (size_t)(k0 + srow) * NPACK + w0 + swd;
  f32x4 acc[2] = {{0,0,0,0},{0,0,0,0}};
  int ngroups = nstep >> 2;
  for (int g = 0; g < ngroups; ++g) {
    int gid = (k0 >> 7) + g;
    float s[2], z[2];
#pragma unroll
    for (int c = 0; c < 2; ++c) {
      int n = n0 + wv * 32 + c * 16 + c15;
      float sv = scales[gid * N_DIM + n];
      int zw = qz[gid * NPACK + w0 + wloc + 2 * c];
      s[c] = sv; z[c] = -sv * (float)((zw >> sh) & 15);
    }
#pragma unroll
    for (int t4 = 0; t4 < 4; ++t4) {
      int kk = g * 4 + t4;
      int2 q2 = *reinterpret_cast<const int2*>(gq + (size_t)kk * 32 * NPACK);
      __syncthreads();
      qt[swd + 0][srow] = q2.x;
      qt[swd + 1][srow] = q2.y;
      __syncthreads();
      const float* xp = x + c15 * K_DIM + k0 + kk * 32 + kg * 8;
      float4 x0 = *reinterpret_cast<const float4*>(xp);
      float4 x1 = *reinterpret_cast<const float4*>(xp + 4);
      union { bf16x8 v; unsigned short u[8]; } a;
      a.u[0]=f2bf(x0.x); a.u[1]=f2bf(x0.y); a.u[2]=f2bf(x0.z); a.u[3]=f2bf(x0.w);
      a.u[4]=f2bf(x1.x); a.u[5]=f2bf(x1.y); a.u[6]=f2bf(x1.z); a.u[7]=f2bf(x1.w);
#pragma unroll
      for (int c = 0; c < 2; ++c) {
        const int* cp = &qt[wloc + 2 * c][kg * 8];
        int4 qa = *reinterpret_cast<const int4*>(cp);
        int4 qb = *reinterpret_cast<const int4*>(cp + 4);
        union { bf16x8 v; unsigned short u[8]; } b;
        float sv = s[c], zv = z[c];
        b.u[0] = f2bf(fmaf((float)((qa.x >> sh) & 15), sv, zv));
        b.u[1] = f2bf(fmaf((float)((qa.y >> sh) & 15), sv, zv));
        b.u[2] = f2bf(fmaf((float)((qa.z >> sh) & 15), sv, zv));
        b.u[3] = f2bf(fmaf((float)((qa.w >> sh) & 15), sv, zv));
        b.u[4] = f2bf(fmaf((float)((qb.x >> sh) & 15), sv, zv));
        b.u[5] = f2bf(fmaf((float)((qb.y >> sh) & 15), sv, zv));
        b.u[6] = f2bf(fmaf((float)((qb.z >> sh) & 15), sv, zv));
        b.u[7] = f2bf(fmaf((float)((qb.w >> sh) & 15), sv, zv));
        acc[c] = __builtin_amdgcn_mfma_f32_16x16x32_bf16(a.v, b.v, acc[c], 0, 0, 0);
      }
    }
  }
  float* pb = part + (size_t)ks * (M_DIM * N_DIM);
#pragma unroll
  for (int c = 0; c < 2; ++c) {
    int n = n0 + wv * 32 + c * 16 + c15;
#pragma unroll
    for (int r = 0; r < 4; ++r)
      pb[(kg * 4 + r) * N_DIM + n] = acc[c][r];
  }
}

// verbatim round-2-proven reduce
__global__ __launch_bounds__(256) void reduce_bias(
    const float* __restrict__ part, const float* __restrict__ bias,
    float* __restrict__ out, int split) {
  int i = blockIdx.x * 256 + threadIdx.x;
  if (i >= (M_DIM * N_DIM) / 4) return;
  int n = (i << 2) % N_DIM;
  float4 a = *reinterpret_cast<const float4*>(bias + n);
  for (int s = 0; s < split; ++s) {
    float4 p = reinterpret_cast<const float4*>(part)[(size_t)s * (M_DIM * N_DIM / 4) + i];
    a.x += p.x; a.y += p.y; a.z += p.z; a.w += p.w;
  }
  reinterpret_cast<float4*>(out)[i] = a;
}

extern "C" void kernel_launch(void* const* d_in, const int* in_sizes, int n_in,
                              void* d_out, int out_size, void* d_ws, size_t ws_size,
                              hipStream_t stream) {
  const float* x      = (const float*)d_in[0];
  const int*   qwp    = (const int*)d_in[1];
  const int*   qzp    = (const int*)d_in[2];
  const float* scales = (const float*)d_in[3];
  const float* bias   = (const float*)d_in[4];
  float* out = (float*)d_out;

  const size_t PART_ELEMS = (size_t)M_DIM * N_DIM;        // 176128
  const size_t PART16_BYTES = 16 * PART_ELEMS * 4;        // 11,272,192

  if (ws_size >= PART16_BYTES) {
    float* part = (float*)d_ws;
    gemm_awq_fast<<<dim3(NCB, 16), 256, 0, stream>>>(qwp, qzp, scales, x, part);
    reduce_bias<<<(M_DIM * N_DIM / 4 + 255) / 256, 256, 0, stream>>>(part, bias, out, 16);
  } else {
    int split = 16;
    while (split > 1 && (size_t)split * PART_ELEMS * 4 > ws_size) split >>= 1;
    float* part = (float*)d_ws;
    if ((size_t)split * PART_ELEMS * 4 > ws_size) {
      split = 1;
      part = out;   // reduce_bias adds bias in place (proven)
    }
    int nstep = 128 / split;
    gemm_awq_generic<<<dim3(NCB, split), 256, 0, stream>>>(qwp, qzp, scales, x, part, nstep);
    reduce_bias<<<(M_DIM * N_DIM / 4 + 255) / 256, 256, 0, stream>>>(part, bias, out, split);
  }
}

// Round 8
// 94.618 us; speedup vs baseline: 1.1407x; 1.1407x over previous
//
#include <hip/hip_runtime.h>

// AWQ W4A16 GEMM: x[16,4096] fp32 * dq(qweight)[4096,11008] + bias.
// Round-8 FINAL-SHAPE: r6 structure (all qweight loads in prologue, dbuf LDS,
// 1 barrier/stage, exact-int MFMA B=128+q with ones-MFMA group fold,
// split-K=16 + reduce). REP diagnostic removed. B-build packed at dword
// level (bfe+bfe+lshl+or3 per 2 elems) to trim the VALU-bound inner loop.
// Measured (r7 slope): gemm ~5.9us/pass, VALU-bound; HBM floor 3.6us.

typedef __attribute__((ext_vector_type(8))) short bf16x8;
typedef __attribute__((ext_vector_type(4))) float f32x4;

#define K_DIM 4096
#define N_DIM 11008
#define M_DIM 16
#define NPACK 1376    // N/8 packed words per k-row
#define NCB   86      // 11008 / 128 cols per block

static __device__ __forceinline__ unsigned short f2bf(float f) {
  unsigned u = __builtin_bit_cast(unsigned, f);
  u += 0x7fffu + ((u >> 16) & 1u);   // RNE, finite only
  return (unsigned short)(u >> 16);
}

// grid (86, 16), block 256 (4 waves). Block: 128 cols (16 words), 256 k.
// 4 stages of BK=64; all stage data loaded to registers in the prologue.
__global__ __launch_bounds__(256) void gemm_awq_fast(
    const int* __restrict__ qw, const int* __restrict__ qz,
    const float* __restrict__ scales, const float* __restrict__ x,
    float* __restrict__ part) {
  // transposed tile [buf][word 0..15][k 0..63], pad 68 ints:
  // fragment reads conflict-free (8 distinct 16B addrs cover all 32 banks);
  // writes <=2-way (free, m136).
  __shared__ int qt[2][16][68];

  int cb = blockIdx.x, ks = blockIdx.y;
  int n0 = cb * 128, w0 = cb * 16, k0 = ks * 256;

  int tid = threadIdx.x, lane = tid & 63, wv = tid >> 6;  // wv 0..3
  int c15 = lane & 15;          // col within 16-tile; also A row m
  int kg  = lane >> 4;          // fragment k-group (8 k)
  int j   = c15 & 7;
  int sh  = ((j & 1) << 4) | ((j >> 1) << 2);  // AWQ {0,4,1,5,2,6,3,7} (proven)
  int wloc = wv * 4 + (c15 >> 3);              // word-in-tile, +2c per col-tile

  // staging: thread t -> k-row t>>2 (0..63), words (t&3)*4 (int4 = 16B)
  int srow = tid >> 2, sw4 = (tid & 3) * 4;
  const int* gq = qw + (size_t)(k0 + srow) * NPACK + w0 + sw4;

  // ---- prologue: issue ALL 4 stage loads first (latency paid once) ----
  int4 qreg[4];
#pragma unroll
  for (int st = 0; st < 4; ++st)
    qreg[st] = *reinterpret_cast<const int4*>(gq + (size_t)st * 64 * NPACK);

  // A fragments from fp32 x: a[kk] = bf16(x[c15][k0+kk*32+kg*8 .. +7])
  bf16x8 a[8];
#pragma unroll
  for (int kk = 0; kk < 8; ++kk) {
    const float* xp = x + c15 * K_DIM + k0 + kk * 32 + kg * 8;
    float4 x0 = *reinterpret_cast<const float4*>(xp);
    float4 x1 = *reinterpret_cast<const float4*>(xp + 4);
    union { bf16x8 v; unsigned short u[8]; } t;
    t.u[0] = f2bf(x0.x); t.u[1] = f2bf(x0.y);
    t.u[2] = f2bf(x0.z); t.u[3] = f2bf(x0.w);
    t.u[4] = f2bf(x1.x); t.u[5] = f2bf(x1.y);
    t.u[6] = f2bf(x1.z); t.u[7] = f2bf(x1.w);
    a[kk] = t.v;
  }

  // scales / zeros for this block's 2 k-groups (hoisted)
  float s[2][2], zn[2][2];
#pragma unroll
  for (int g = 0; g < 2; ++g) {
    int gid = ks * 2 + g;
#pragma unroll
    for (int c = 0; c < 2; ++c) {
      int n = n0 + wv * 32 + c * 16 + c15;
      s[g][c] = scales[gid * N_DIM + n];
      int zw = qz[gid * NPACK + w0 + wloc + 2 * c];
      zn[g][c] = -(float)(((zw >> sh) & 15) + 128);  // -(z+128)
    }
  }

  union { bf16x8 v; unsigned short u[8]; } ones;
#pragma unroll
  for (int i = 0; i < 8; ++i) ones.u[i] = 0x3F80;  // bf16 1.0

  const f32x4 vzero = {0.f, 0.f, 0.f, 0.f};
  f32x4 macc[2] = {vzero, vzero};
  f32x4 pacc[2] = {vzero, vzero};
  f32x4 xacc    = vzero;

  // stage 0 into buf 0 (data already in flight)
  qt[0][sw4 + 0][srow] = qreg[0].x;
  qt[0][sw4 + 1][srow] = qreg[0].y;
  qt[0][sw4 + 2][srow] = qreg[0].z;
  qt[0][sw4 + 3][srow] = qreg[0].w;
  __syncthreads();

#pragma unroll
  for (int st = 0; st < 4; ++st) {
    const int cur = st & 1;

#pragma unroll
    for (int t2 = 0; t2 < 2; ++t2) {
      const int kk = st * 2 + t2;
#pragma unroll
      for (int c = 0; c < 2; ++c) {
        const int* cp = &qt[cur][wloc + 2 * c][t2 * 32 + kg * 8];
        int4 qa = *reinterpret_cast<const int4*>(cp);      // ds_read_b128
        int4 qb = *reinterpret_cast<const int4*>(cp + 4);  // ds_read_b128
        // B = bf16(128 + nibble) exactly: dword = 0x43004300 | lo | hi<<16
        union { bf16x8 v; unsigned d[4]; } b;
        b.d[0] = 0x43004300u | (unsigned)((qa.x >> sh) & 15)
                             | ((unsigned)((qa.y >> sh) & 15) << 16);
        b.d[1] = 0x43004300u | (unsigned)((qa.z >> sh) & 15)
                             | ((unsigned)((qa.w >> sh) & 15) << 16);
        b.d[2] = 0x43004300u | (unsigned)((qb.x >> sh) & 15)
                             | ((unsigned)((qb.y >> sh) & 15) << 16);
        b.d[3] = 0x43004300u | (unsigned)((qb.z >> sh) & 15)
                             | ((unsigned)((qb.w >> sh) & 15) << 16);
        pacc[c] = __builtin_amdgcn_mfma_f32_16x16x32_bf16(a[kk], b.v, pacc[c], 0, 0, 0);
      }
      xacc = __builtin_amdgcn_mfma_f32_16x16x32_bf16(a[kk], ones.v, xacc, 0, 0, 0);

      if ((kk & 3) == 3) {  // group fold: macc += s * (P' + (-(z+128))*X)
        const int g = kk >> 2;
#pragma unroll
        for (int c = 0; c < 2; ++c)
#pragma unroll
          for (int r = 0; r < 4; ++r) {
            float t = fmaf(zn[g][c], xacc[r], pacc[c][r]);
            macc[c][r] = fmaf(s[g][c], t, macc[c][r]);
          }
        pacc[0] = vzero; pacc[1] = vzero; xacc = vzero;
      }
    }

    if (st < 3) {  // write next stage from registers into the other buffer
      qt[cur ^ 1][sw4 + 0][srow] = qreg[st + 1].x;
      qt[cur ^ 1][sw4 + 1][srow] = qreg[st + 1].y;
      qt[cur ^ 1][sw4 + 2][srow] = qreg[st + 1].z;
      qt[cur ^ 1][sw4 + 3][srow] = qreg[st + 1].w;
    }
    __syncthreads();
  }

  // epilogue: D col = lane&15, row = (lane>>4)*4 + r (m89-verified)
  float* pb = part + (size_t)ks * (M_DIM * N_DIM);
#pragma unroll
  for (int c = 0; c < 2; ++c) {
    int n = n0 + wv * 32 + c * 16 + c15;
#pragma unroll
    for (int r = 0; r < 4; ++r)
      pb[(kg * 4 + r) * N_DIM + n] = macc[c][r];
  }
}

// Generic fallback (round-3-proven verbatim), used only if ws is tiny.
__global__ __launch_bounds__(256) void gemm_awq_generic(
    const int* __restrict__ qw, const int* __restrict__ qz,
    const float* __restrict__ scales, const float* __restrict__ x,
    float* __restrict__ part, int nstep) {
  __shared__ int qt[16][36];
  int cb = blockIdx.x, ks = blockIdx.y;
  int n0 = cb * 128, w0 = cb * 16, k0 = ks * nstep * 32;
  int tid = threadIdx.x, lane = tid & 63, wv = tid >> 6;
  int c15 = lane & 15, kg = lane >> 4;
  int j = c15 & 7;
  int sh = ((j & 1) << 4) | ((j >> 1) << 2);
  int wloc = wv * 4 + (c15 >> 3);
  int srow = tid >> 3, swd = (tid & 7) * 2;
  const int* gq = qw + (size_t)(k0 + srow) * NPACK + w0 + swd;
  f32x4 acc[2] = {{0,0,0,0},{0,0,0,0}};
  int ngroups = nstep >> 2;
  for (int g = 0; g < ngroups; ++g) {
    int gid = (k0 >> 7) + g;
    float s[2], z[2];
#pragma unroll
    for (int c = 0; c < 2; ++c) {
      int n = n0 + wv * 32 + c * 16 + c15;
      float sv = scales[gid * N_DIM + n];
      int zw = qz[gid * NPACK + w0 + wloc + 2 * c];
      s[c] = sv; z[c] = -sv * (float)((zw >> sh) & 15);
    }
#pragma unroll
    for (int t4 = 0; t4 < 4; ++t4) {
      int kk = g * 4 + t4;
      int2 q2 = *reinterpret_cast<const int2*>(gq + (size_t)kk * 32 * NPACK);
      __syncthreads();
      qt[swd + 0][srow] = q2.x;
      qt[swd + 1][srow] = q2.y;
      __syncthreads();
      const float* xp = x + c15 * K_DIM + k0 + kk * 32 + kg * 8;
      float4 x0 = *reinterpret_cast<const float4*>(xp);
      float4 x1 = *reinterpret_cast<const float4*>(xp + 4);
      union { bf16x8 v; unsigned short u[8]; } a;
      a.u[0]=f2bf(x0.x); a.u[1]=f2bf(x0.y); a.u[2]=f2bf(x0.z); a.u[3]=f2bf(x0.w);
      a.u[4]=f2bf(x1.x); a.u[5]=f2bf(x1.y); a.u[6]=f2bf(x1.z); a.u[7]=f2bf(x1.w);
#pragma unroll
      for (int c = 0; c < 2; ++c) {
        const int* cp = &qt[wloc + 2 * c][kg * 8];
        int4 qa = *reinterpret_cast<const int4*>(cp);
        int4 qb = *reinterpret_cast<const int4*>(cp + 4);
        union { bf16x8 v; unsigned short u[8]; } b;
        float sv = s[c], zv = z[c];
        b.u[0] = f2bf(fmaf((float)((qa.x >> sh) & 15), sv, zv));
        b.u[1] = f2bf(fmaf((float)((qa.y >> sh) & 15), sv, zv));
        b.u[2] = f2bf(fmaf((float)((qa.z >> sh) & 15), sv, zv));
        b.u[3] = f2bf(fmaf((float)((qa.w >> sh) & 15), sv, zv));
        b.u[4] = f2bf(fmaf((float)((qb.x >> sh) & 15), sv, zv));
        b.u[5] = f2bf(fmaf((float)((qb.y >> sh) & 15), sv, zv));
        b.u[6] = f2bf(fmaf((float)((qb.z >> sh) & 15), sv, zv));
        b.u[7] = f2bf(fmaf((float)((qb.w >> sh) & 15), sv, zv));
        acc[c] = __builtin_amdgcn_mfma_f32_16x16x32_bf16(a.v, b.v, acc[c], 0, 0, 0);
      }
    }
  }
  float* pb = part + (size_t)ks * (M_DIM * N_DIM);
#pragma unroll
  for (int c = 0; c < 2; ++c) {
    int n = n0 + wv * 32 + c * 16 + c15;
#pragma unroll
    for (int r = 0; r < 4; ++r)
      pb[(kg * 4 + r) * N_DIM + n] = acc[c][r];
  }
}

// verbatim round-2-proven reduce
__global__ __launch_bounds__(256) void reduce_bias(
    const float* __restrict__ part, const float* __restrict__ bias,
    float* __restrict__ out, int split) {
  int i = blockIdx.x * 256 + threadIdx.x;
  if (i >= (M_DIM * N_DIM) / 4) return;
  int n = (i << 2) % N_DIM;
  float4 a = *reinterpret_cast<const float4*>(bias + n);
  for (int s = 0; s < split; ++s) {
    float4 p = reinterpret_cast<const float4*>(part)[(size_t)s * (M_DIM * N_DIM / 4) + i];
    a.x += p.x; a.y += p.y; a.z += p.z; a.w += p.w;
  }
  reinterpret_cast<float4*>(out)[i] = a;
}

extern "C" void kernel_launch(void* const* d_in, const int* in_sizes, int n_in,
                              void* d_out, int out_size, void* d_ws, size_t ws_size,
                              hipStream_t stream) {
  const float* x      = (const float*)d_in[0];
  const int*   qwp    = (const int*)d_in[1];
  const int*   qzp    = (const int*)d_in[2];
  const float* scales = (const float*)d_in[3];
  const float* bias   = (const float*)d_in[4];
  float* out = (float*)d_out;

  const size_t PART_ELEMS = (size_t)M_DIM * N_DIM;        // 176128
  const size_t PART16_BYTES = 16 * PART_ELEMS * 4;        // 11,272,192

  if (ws_size >= PART16_BYTES) {
    float* part = (float*)d_ws;
    gemm_awq_fast<<<dim3(NCB, 16), 256, 0, stream>>>(qwp, qzp, scales, x, part);
    reduce_bias<<<(M_DIM * N_DIM / 4 + 255) / 256, 256, 0, stream>>>(part, bias, out, 16);
  } else {
    int split = 16;
    while (split > 1 && (size_t)split * PART_ELEMS * 4 > ws_size) split >>= 1;
    float* part = (float*)d_ws;
    if ((size_t)split * PART_ELEMS * 4 > ws_size) {
      split = 1;
      part = out;   // reduce_bias adds bias in place (proven)
    }
    int nstep = 128 / split;
    gemm_awq_generic<<<dim3(NCB, split), 256, 0, stream>>>(qwp, qzp, scales, x, part, nstep);
    reduce_bias<<<(M_DIM * N_DIM / 4 + 255) / 256, 256, 0, stream>>>(part, bias, out, split);
  }
}